// Round 2
// baseline (238.430 us; speedup 1.0000x reference)
//
#include <hip/hip_runtime.h>

// DCE-MRI eTofts forward model — single-wave-workgroup, line-aligned tiles.
// param: [B,3] f32, T10: [B,1] f32, cp: [B,T] f32  ->  out: [B,T] f32
//
// Block = 64 threads = ONE wave; each wave owns 64 consecutive rows and its
// own private LDS. With a single-wave workgroup, __syncthreads() degenerates
// to an intra-wave waitcnt (no inter-wave lockstep), so every wave free-runs
// its own load -> stage -> compute -> store pipeline.
//
// T tiled 7 x 16: each row-tile is exactly 64 B (one cache line), aligned
// (row stride 448 B = 7 lines), so every global load/store instruction covers
// full aligned lines — no partial-line RMW on stores, no over-fetch on loads.
// Index math is pure shift/mask.
//
// Pipeline: prefetch tile k+1 into registers (4 float4/lane, coalesced) while
// computing tile k from LDS. LDS transposed: sl[t*65 + row]; compute reads
// sl[t*65 + lane] -> bank (t+lane)%32, 2 lanes/bank = conflict-free (m136).
//
// NOTE: __builtin_nontemporal_load/store require native Clang vector types,
// not HIP_vector_type<float,4> — use ext_vector_type(4).

typedef float f32x4 __attribute__((ext_vector_type(4)));

static constexpr int   Bn    = 262144;
static constexpr int   Tn    = 112;
static constexpr int   TT    = 16;         // timesteps per tile (64 B per row-tile)
static constexpr int   NT    = Tn / TT;    // 7 tiles
static constexpr int   LP    = 65;         // LDS stride between t-rows (pad)
static constexpr float TRc   = 0.005f;
static constexpr float DELTT = 0.075f;                 // 4.5/60
static constexpr float R1R   = 4.5f;
static constexpr float SIN_A = 0.25881904510252074f;   // sin(15 deg)
static constexpr float COS_A = 0.9659258262890683f;    // cos(15 deg)

__global__ __launch_bounds__(64) void etofts_kernel(
    const float* __restrict__ param,
    const float* __restrict__ T10,
    const float* __restrict__ cp,
    float* __restrict__ out)
{
    __shared__ float sl[TT * LP];          // 16*65*4 = 4160 B (wave-private)

    const int l  = threadIdx.x;            // lane 0..63
    const int b0 = blockIdx.x * 64;        // this wave's first row
    const int b  = b0 + l;                 // this lane's own row

    // Parameter scaling + clamping (issue these loads first; they overlap
    // with the tile-0 cp prefetch below)
    const float ktrans = fminf(fmaxf(param[3 * b + 0] * 0.2f, 1e-5f), 0.2f);
    const float vp     = fminf(fmaxf(param[3 * b + 1] * 0.1f, 0.0005f), 0.1f);
    const float ve     = fminf(fmaxf(param[3 * b + 2] * 0.6f, 0.04f), 0.6f);
    const float decay  = __expf(-(ktrans / ve) * DELTT);
    const float r10    = 1.0f / T10[b];

    // Per-lane load/store mapping: idx = i*64 + l, row = idx/4, c4 = idx%4.
    // Since i*64 is a multiple of 64: row = i*16 + (l>>2), c4 = l&3.
    // Each instruction covers contiguous aligned 64 B per 4-lane group.
    const int rsub = l >> 2;               // 0..15  (row within 16-row group)
    const int c4   = l & 3;                // 0..3   (float4 column)
    const int tb   = c4 * 4;               // first timestep of this float4

    // ---- prefetch tile 0 into registers (coalesced, full-line loads) ----
    f32x4 r[4];
    #pragma unroll
    for (int i = 0; i < 4; ++i) {
        const int row = i * 16 + rsub;
        r[i] = __builtin_nontemporal_load(
            (const f32x4*)(cp + (size_t)(b0 + row) * Tn + c4 * 4));
    }

    float c = 0.0f;                        // IIR state across tiles

    #pragma unroll
    for (int tile = 0; tile < NT; ++tile) {
        // ---- stage prefetched registers into transposed LDS ----
        #pragma unroll
        for (int i = 0; i < 4; ++i) {
            const int row = i * 16 + rsub;
            sl[(tb + 0) * LP + row] = r[i].x;
            sl[(tb + 1) * LP + row] = r[i].y;
            sl[(tb + 2) * LP + row] = r[i].z;
            sl[(tb + 3) * LP + row] = r[i].w;
        }
        __syncthreads();                   // single-wave: cheap

        // ---- issue next tile's loads NOW (hide HBM latency behind compute) ----
        if (tile + 1 < NT) {
            #pragma unroll
            for (int i = 0; i < 4; ++i) {
                const int row = i * 16 + rsub;
                r[i] = __builtin_nontemporal_load(
                    (const f32x4*)(cp + (size_t)(b0 + row) * Tn
                                   + (tile + 1) * TT + c4 * 4));
            }
        }

        // ---- compute in place (own column: no cross-lane race) ----
        #pragma unroll
        for (int t = 0; t < TT; ++t) {
            const float cpt = sl[t * LP + l];
            c = fmaf(c, decay, cpt * DELTT);             // IIR recurrence
            const float ct = fmaf(c, ktrans, vp * cpt);  // vp*cp + ce
            const float E  = __expf(-TRc * fmaf(R1R, ct, r10));
            sl[t * LP + l] = __fdividef((1.0f - E) * (SIN_A * 20.0f),
                                        fmaf(-E, COS_A, 1.0f));
        }
        __syncthreads();

        // ---- coalesced full-line store from transposed LDS ----
        #pragma unroll
        for (int i = 0; i < 4; ++i) {
            const int row = i * 16 + rsub;
            f32x4 o;
            o.x = sl[(tb + 0) * LP + row];
            o.y = sl[(tb + 1) * LP + row];
            o.z = sl[(tb + 2) * LP + row];
            o.w = sl[(tb + 3) * LP + row];
            __builtin_nontemporal_store(
                o, (f32x4*)(out + (size_t)(b0 + row) * Tn + tile * TT + c4 * 4));
        }
        __syncthreads();   // protect LDS before next tile's staging overwrites
    }
}

extern "C" void kernel_launch(void* const* d_in, const int* in_sizes, int n_in,
                              void* d_out, int out_size, void* d_ws, size_t ws_size,
                              hipStream_t stream) {
    const float* param = (const float*)d_in[0];
    const float* T10   = (const float*)d_in[1];
    const float* cp    = (const float*)d_in[2];
    float*       out   = (float*)d_out;

    const int threads = 64;
    const int blocks  = Bn / 64;           // 4096 single-wave workgroups
    etofts_kernel<<<blocks, threads, 0, stream>>>(param, T10, cp, out);
}